// Round 2
// baseline (339.537 us; speedup 1.0000x reference)
//
#include <hip/hip_runtime.h>
#include <hip/hip_bf16.h>

#define NQ 4096
#define NK 8192
#define DQK 256
#define DA 64
#define NH 4
#define DOUT 256
#define NQT (NQ / 32)        // 128 q-tiles of 32
#define NSUP 8               // surviving partials per (h,qt): 8 key-pairs
#define LOG2E 1.44269504088896340736f
#define QSCALE (0.125f * LOG2E)   // 1/sqrt(64) * log2(e), folded into Qp

typedef __attribute__((ext_vector_type(8))) short bf16x8;
typedef __attribute__((ext_vector_type(4))) float f32x4;
typedef __attribute__((ext_vector_type(4))) _Float16 f16x4;
typedef __attribute__((ext_vector_type(8))) _Float16 f16x8;

__device__ inline unsigned short f2bf(float f) {
  union { float f; unsigned u; } v; v.f = f;
  unsigned r = v.u + 0x7fff + ((v.u >> 16) & 1);  // RNE
  return (unsigned short)(r >> 16);
}

// ---------------------------------------------------------------------------
// 1. mask (int32 NQ x NK) -> TRANSPOSED bitmask bitsT[word32][row] (4 MB).
//    attn then reads 16 consecutive rows' words as one 64B segment.
// ---------------------------------------------------------------------------
__global__ __launch_bounds__(256) void maskbits_kernel(
    const int* __restrict__ mask, unsigned* __restrict__ bitsT) {
  const int NW = 8192 * 4;                       // total waves
  int wid = blockIdx.x * 4 + (threadIdx.x >> 6);
  int lane = threadIdx.x & 63;
  for (int j = 0; j < 2; ++j) {
    int v[8];
#pragma unroll
    for (int u = 0; u < 8; ++u) {
      int c = wid + (j * 8 + u) * NW;   // u64 chunk id: row = c>>7, ch = c&127
      v[u] = mask[(size_t)(c >> 7) * NK + (c & 127) * 64 + lane];
    }
#pragma unroll
    for (int u = 0; u < 8; ++u) {
      unsigned long long b = __ballot(v[u] != 0);
      int c = wid + (j * 8 + u) * NW;
      int n = c >> 7, ch = c & 127;
      if (lane == 0)  bitsT[(size_t)(2 * ch) * NQ + n] = (unsigned)b;
      if (lane == 32) bitsT[(size_t)(2 * ch + 1) * NQ + n] = (unsigned)(b >> 32);
    }
  }
}

// ---------------------------------------------------------------------------
// 2. projections: Q = xQ@Wq[h] * QSCALE -> Qp[h][n][d] bf16 (scale folded)
//                 K = xK@Wk[h] -> Kp[h][m][d] bf16
//                 V -> Vf f16 in K=32 fragment-linear order (PV A-frags).
// ---------------------------------------------------------------------------
__global__ __launch_bounds__(256) void proj_kernel(
    const float* __restrict__ xQ, const float* __restrict__ xK,
    const float* __restrict__ Wq, const float* __restrict__ Wk,
    const float* __restrict__ Wv,
    unsigned short* __restrict__ Qp, unsigned short* __restrict__ Kp,
    _Float16* __restrict__ Vf) {
  __shared__ __align__(16) unsigned short Wt[64][264];  // Wt[d][c], padded

  int b = blockIdx.x;
  int proj, h, rb;
  if (b < 128)       { proj = 0; h = b >> 5;  rb = b & 31; }
  else if (b < 384)  { proj = 1; b -= 128; h = b >> 6; rb = b & 63; }
  else               { proj = 2; b -= 384; h = b >> 6; rb = b & 63; }
  const float* x = (proj == 0) ? xQ : xK;
  const float* W = (proj == 0 ? Wq : (proj == 1 ? Wk : Wv)) + (size_t)h * 256 * 64;

  for (int i = threadIdx.x; i < 16384; i += 256)
    Wt[i & 63][i >> 6] = f2bf(W[i]);
  __syncthreads();

  int lane = threadIdx.x & 63, wv = threadIdx.x >> 6;
  int quad = lane >> 4, n16 = lane & 15;
  int r0 = rb * 128 + wv * 32;          // 32 rows per wave

  f32x4 acc[2][4];
#pragma unroll
  for (int mt = 0; mt < 2; ++mt)
#pragma unroll
    for (int nt = 0; nt < 4; ++nt)
      acc[mt][nt] = (f32x4){0.f, 0.f, 0.f, 0.f};

#pragma unroll
  for (int it = 0; it < 8; ++it) {
    const int k0 = it * 32;
    bf16x8 af[2];
#pragma unroll
    for (int mt = 0; mt < 2; ++mt) {
      const float* xp = x + (size_t)(r0 + mt * 16 + n16) * 256 + k0 + quad * 8;
      const float4 a0 = *(const float4*)xp;
      const float4 a1 = *(const float4*)(xp + 4);
      bf16x8 a;
      a[0] = (short)f2bf(a0.x); a[1] = (short)f2bf(a0.y);
      a[2] = (short)f2bf(a0.z); a[3] = (short)f2bf(a0.w);
      a[4] = (short)f2bf(a1.x); a[5] = (short)f2bf(a1.y);
      a[6] = (short)f2bf(a1.z); a[7] = (short)f2bf(a1.w);
      af[mt] = a;
    }
    bf16x8 bfr[4];
#pragma unroll
    for (int nt = 0; nt < 4; ++nt)
      bfr[nt] = *(const bf16x8*)&Wt[nt * 16 + n16][k0 + quad * 8];
#pragma unroll
    for (int mt = 0; mt < 2; ++mt)
#pragma unroll
      for (int nt = 0; nt < 4; ++nt)
        acc[mt][nt] = __builtin_amdgcn_mfma_f32_16x16x32_bf16(
            af[mt], bfr[nt], acc[mt][nt], 0, 0, 0);
  }

  if (proj < 2) {
    unsigned short* outp =
        (proj == 0 ? Qp : Kp) + (size_t)h * (size_t)(proj == 0 ? NQ : NK) * 64;
    const float sc = (proj == 0) ? QSCALE : 1.0f;
#pragma unroll
    for (int mt = 0; mt < 2; ++mt)
#pragma unroll
      for (int nt = 0; nt < 4; ++nt)
#pragma unroll
        for (int r = 0; r < 4; ++r) {
          int row = r0 + mt * 16 + quad * 4 + r;
          int col = nt * 16 + n16;
          outp[(size_t)row * 64 + col] = f2bf(acc[mt][nt][r] * sc);
        }
  } else {
    // K=32 fragment-linear V: tile = h*256 + keyblock32; frag dt holds
    // lane's f16x8 = {acc[mt0][dt][0..3], acc[mt1][dt][0..3]} (16B stores)
    int tile = h * 256 + (r0 >> 5);     // r0 is 32-aligned, mt0/mt1 same tile
#pragma unroll
    for (int nt = 0; nt < 4; ++nt) {
      f16x8 pk;
      pk[0] = (_Float16)acc[0][nt][0]; pk[1] = (_Float16)acc[0][nt][1];
      pk[2] = (_Float16)acc[0][nt][2]; pk[3] = (_Float16)acc[0][nt][3];
      pk[4] = (_Float16)acc[1][nt][0]; pk[5] = (_Float16)acc[1][nt][1];
      pk[6] = (_Float16)acc[1][nt][2]; pk[7] = (_Float16)acc[1][nt][3];
      *(f16x8*)&Vf[(((size_t)tile * 4 + nt) * 64 + lane) * 8] = pk;
    }
  }
}

// ---------------------------------------------------------------------------
// 3. flash attention, S^T formulation, fixed max, in-register P.
//    Round-2 restructure: block = (h, key-pair kp, q-tile-group) x 4 waves.
//    - All 4 waves share the SAME (h, kp) key stream, differing only in
//      q-tile -> sibling waves hit L1 on K/V/bits (8KB/kb vs 32KB L1),
//      cutting L1->L2 read pressure ~4x (the round-1 bottleneck).
//    - Each wave covers 2 adjacent key-splits (1024 keys, 32 kb); fixed-max
//      exp2 partials just add, so one partial per wave -> NSUP=8.
//    - grid = 1024 = exactly one occupancy round at 4 blocks/CU; no LDS,
//      no __syncthreads, no cross-wave reduction in attn at all.
//    - manual ping-pong double-buffer (kA/kB): no register copies.
//    - XCD-chunked swizzle: each XCD owns 1 head x 4 key-pairs
//      (KV 1MB + Q 0.5MB + bits 2MB < 4MB per-XCD L2).
// ---------------------------------------------------------------------------
__global__ __launch_bounds__(256, 4) void attn_kernel(
    const unsigned short* __restrict__ Qp, const unsigned short* __restrict__ Kp,
    const _Float16* __restrict__ Vf, const unsigned* __restrict__ bitsT,
    _Float16* __restrict__ Opart, float* __restrict__ Lpart) {
  // bijective XCD swizzle (8 XCDs, 1024 blocks, 128/chunk)
  int orig = blockIdx.x;
  int wgid = (orig & 7) * 128 + (orig >> 3);
  int qtg = wgid & 31;
  int combo = wgid >> 5;          // h*8 + kp: each XCD owns 4 combos, same h
  int kp = combo & 7, h = combo >> 3;

  int wv = threadIdx.x >> 6, lane = threadIdx.x & 63;
  int quad = lane >> 4, n16 = lane & 15;
  int qt = qtg * 4 + wv;          // this wave's q-tile
  int qb = qt * 32;

  // Q frags (bf16, pre-scaled by QSCALE)
  bf16x8 qf[2][2];
#pragma unroll
  for (int qc = 0; qc < 2; ++qc)
#pragma unroll
    for (int c = 0; c < 2; ++c)
      qf[qc][c] = *(const bf16x8*)&Qp[((size_t)h * NQ + qb + qc * 16 + n16) * 64 +
                                      c * 32 + quad * 8];

  f32x4 o[4][2];
#pragma unroll
  for (int dt = 0; dt < 4; ++dt)
#pragma unroll
    for (int qc = 0; qc < 2; ++qc) o[dt][qc] = (f32x4){0.f, 0.f, 0.f, 0.f};
  f32x4 o_l[2];
  o_l[0] = (f32x4){0.f, 0.f, 0.f, 0.f};
  o_l[1] = (f32x4){0.f, 0.f, 0.f, 0.f};

  f16x8 vones;
#pragma unroll
  for (int i = 0; i < 8; ++i) vones[i] = (_Float16)1.0f;

  const unsigned short* Kptr =
      Kp + (size_t)h * NK * 64 + (size_t)(kp * 1024 + n16) * 64 + quad * 8;
  const _Float16* Vbase = Vf + ((size_t)h * 256 + kp * 32) * 2048 + lane * 8;
  const unsigned* bT = bitsT + (size_t)(kp * 32) * NQ + qb;

  const int NKB = 32;   // 1024 keys = 32 blocks of 32

  auto prefK = [&](int kb, bf16x8 (&kf)[2][2], unsigned& w0, unsigned& w1) {
    w0 = bT[(size_t)kb * NQ + n16];
    w1 = bT[(size_t)kb * NQ + 16 + n16];
    const unsigned short* Kg = Kptr + (size_t)kb * 2048;
#pragma unroll
    for (int kr = 0; kr < 2; ++kr)
#pragma unroll
      for (int c = 0; c < 2; ++c)
        kf[kr][c] = *(const bf16x8*)(Kg + kr * 16 * 64 + c * 32);
  };

  auto body = [&](int kb, const bf16x8 (&kf)[2][2], unsigned wqa0, unsigned wqa1) {
    // V A-frags: K=32 fragment-linear, 16B loads (consumed last -> latency
    // hidden under QK + exp)
    const _Float16* Vg = Vbase + (size_t)kb * 2048;
    f16x8 vf8[4];
#pragma unroll
    for (int dt = 0; dt < 4; ++dt)
      vf8[dt] = *(const f16x8*)(Vg + dt * 512);

    // S^T = K·Q^T (bf16 K=32, pre-scaled)
    f32x4 s[2][2];
#pragma unroll
    for (int kr = 0; kr < 2; ++kr)
#pragma unroll
      for (int qc = 0; qc < 2; ++qc) {
        f32x4 acc = (f32x4){0.f, 0.f, 0.f, 0.f};
        acc = __builtin_amdgcn_mfma_f32_16x16x32_bf16(kf[kr][0], qf[qc][0], acc, 0, 0, 0);
        acc = __builtin_amdgcn_mfma_f32_16x16x32_bf16(kf[kr][1], qf[qc][1], acc, 0, 0, 0);
        s[kr][qc] = acc;
      }

    // P = exp2(S^T) masked -> f16x8 B-frag (kr0 in elems 0..3, kr1 in 4..7,
    // matching the V storage permutation)
#pragma unroll
    for (int qc = 0; qc < 2; ++qc) {
      unsigned wq = (qc == 0 ? wqa0 : wqa1) >> (quad * 4);
      f16x8 pf8;
#pragma unroll
      for (int kr = 0; kr < 2; ++kr) {
        float e0 = __builtin_amdgcn_exp2f(s[kr][qc][0]);
        float e1 = __builtin_amdgcn_exp2f(s[kr][qc][1]);
        float e2 = __builtin_amdgcn_exp2f(s[kr][qc][2]);
        float e3 = __builtin_amdgcn_exp2f(s[kr][qc][3]);
        e0 = (wq & (1u << (kr * 16 + 0))) ? e0 : 0.f;
        e1 = (wq & (1u << (kr * 16 + 1))) ? e1 : 0.f;
        e2 = (wq & (1u << (kr * 16 + 2))) ? e2 : 0.f;
        e3 = (wq & (1u << (kr * 16 + 3))) ? e3 : 0.f;
        pf8[kr * 4 + 0] = (_Float16)e0; pf8[kr * 4 + 1] = (_Float16)e1;
        pf8[kr * 4 + 2] = (_Float16)e2; pf8[kr * 4 + 3] = (_Float16)e3;
      }
      // l-sum on the MFMA pipe: ones-A-frag, every reg of o_l = sum_k P[k][q]
      o_l[qc] = __builtin_amdgcn_mfma_f32_16x16x32_f16(vones, pf8, o_l[qc], 0, 0, 0);
#pragma unroll
      for (int dt = 0; dt < 4; ++dt)
        o[dt][qc] = __builtin_amdgcn_mfma_f32_16x16x32_f16(vf8[dt], pf8,
                                                           o[dt][qc], 0, 0, 0);
    }
  };

  // ---- ping-pong double-buffered K-loop (no register copies)
  bf16x8 kA[2][2], kB[2][2];
  unsigned wA0, wA1, wB0, wB1;
  prefK(0, kA, wA0, wA1);
  for (int kb = 0; kb < NKB; kb += 2) {
    prefK(kb + 1, kB, wB0, wB1);
    body(kb, kA, wA0, wA1);
    prefK(kb + 2 < NKB ? kb + 2 : 0, kA, wA0, wA1);   // last one harmless
    body(kb + 1, kB, wB0, wB1);
  }

  // ---- direct per-wave store (no cross-wave reduction needed)
  const size_t tile = ((size_t)h * NQT + qt) * NSUP + kp;
#pragma unroll
  for (int qc = 0; qc < 2; ++qc) {
#pragma unroll
    for (int dt = 0; dt < 4; ++dt) {
      f16x4 ov;
      ov[0] = (_Float16)o[dt][qc][0]; ov[1] = (_Float16)o[dt][qc][1];
      ov[2] = (_Float16)o[dt][qc][2]; ov[3] = (_Float16)o[dt][qc][3];
      *(f16x4*)&Opart[(tile * 32 + qc * 16 + n16) * 64 + dt * 16 + quad * 4] = ov;
    }
    if (quad == 0) Lpart[tile * 32 + qc * 16 + n16] = o_l[qc][0];
  }
}

// ---------------------------------------------------------------------------
// 4. combine NSUP partials + fused gates + @Wo + bo. 256 blocks x 16 rows
// ---------------------------------------------------------------------------
__global__ __launch_bounds__(256) void combine_kernel(
    const _Float16* __restrict__ Opart, const float* __restrict__ Lpart,
    const float* __restrict__ xQ, const float* __restrict__ Wg,
    const float* __restrict__ bg, const float* __restrict__ Wo,
    const float* __restrict__ bo, float* __restrict__ out) {
  __shared__ float comb[16][64];
  __shared__ float gred[16][4][4];
  __shared__ float glds[16][4];
  int nb = blockIdx.x;
  int tid = threadIdx.x;

  // gates for this block's 16 rows
  {
    int r = tid >> 4, hh = (tid >> 2) & 3, c = tid & 3;
    const float* xp = xQ + (size_t)(nb * 16 + r) * 256 + c * 64;
    const float* wp = Wg + hh * 256 + c * 64;
    float s = 0.f;
#pragma unroll
    for (int e = 0; e < 64; ++e) s = fmaf(xp[e], wp[e], s);
    gred[r][hh][c] = s;
  }
  __syncthreads();
  if (tid < 64) {
    int r = tid >> 2, hh = tid & 3;
    float s = gred[r][hh][0] + gred[r][hh][1] + gred[r][hh][2] + gred[r][hh][3];
    glds[r][hh] = 1.f / (1.f + __expf(-(s + bg[hh])));
  }
  __syncthreads();

  int r4 = tid >> 6, a = tid & 63;
  int qt = nb >> 1, rbase = (nb & 1) * 16;

  for (int p = 0; p < 4; ++p) {
    int r = p * 4 + r4;
    int rl = rbase + r;
    float csum = 0.f;
#pragma unroll
    for (int h = 0; h < NH; ++h) {
      size_t t0 = ((size_t)h * NQT + qt) * NSUP;
      float accO = 0.f, lt = 0.f;
#pragma unroll
      for (int s = 0; s < NSUP; ++s) {
        size_t t = t0 + s;
        accO += (float)Opart[(t * 32 + rl) * 64 + a];
        lt += Lpart[t * 32 + rl];
      }
      csum += glds[r][h] * accO / lt;
    }
    comb[r][a] = csum;
  }
  __syncthreads();

  int j = tid;
  float accv[16];
#pragma unroll
  for (int r = 0; r < 16; ++r) accv[r] = bo[j];
  for (int aa = 0; aa < 64; ++aa) {
    float w = Wo[(size_t)aa * 256 + j];
#pragma unroll
    for (int r = 0; r < 16; ++r) accv[r] = fmaf(comb[r][aa], w, accv[r]);
  }
#pragma unroll
  for (int r = 0; r < 16; ++r)
    out[(size_t)(nb * 16 + r) * 256 + j] = accv[r];
}

// ---------------------------------------------------------------------------
extern "C" void kernel_launch(void* const* d_in, const int* in_sizes, int n_in,
                              void* d_out, int out_size, void* d_ws, size_t ws_size,
                              hipStream_t stream) {
  const float* xQ  = (const float*)d_in[0];
  const float* xK  = (const float*)d_in[1];
  const int*   mask= (const int*)d_in[2];
  const float* Wq  = (const float*)d_in[3];
  const float* Wk  = (const float*)d_in[4];
  const float* Wv  = (const float*)d_in[5];
  const float* Wg  = (const float*)d_in[6];
  const float* bg  = (const float*)d_in[7];
  const float* Wo  = (const float*)d_in[8];
  const float* bo  = (const float*)d_in[9];
  float* out = (float*)d_out;

  char* ws = (char*)d_ws;
  unsigned short* Qp   = (unsigned short*)(ws + 0);         // 2 MB   [H][NQ][64]
  unsigned short* Kp   = (unsigned short*)(ws + 2097152);   // 4 MB   [H][NK][64]
  _Float16*       Vfp  = (_Float16*)(ws + 6291456);         // 4 MB   frag-linear
  unsigned*       bitsT= (unsigned*)(ws + 10485760);        // 4 MB   [word][row]
  float*          Lp   = (float*)(ws + 14680064);           // 512 KB (4096 tiles)
  _Float16*       Op   = (_Float16*)(ws + 15204352);        // 16.8 MB f16

  maskbits_kernel<<<dim3(8192), dim3(256), 0, stream>>>(mask, bitsT);
  proj_kernel<<<dim3(640), dim3(256), 0, stream>>>(xQ, xK, Wq, Wk, Wv, Qp, Kp, Vfp);
  attn_kernel<<<dim3(1024), dim3(256), 0, stream>>>(Qp, Kp, Vfp, bitsT, Op, Lp);
  combine_kernel<<<dim3(NQ / 16), dim3(256), 0, stream>>>(Op, Lp, xQ, Wg, bg,
                                                          Wo, bo, out);
}

// Round 4
// 303.922 us; speedup vs baseline: 1.1172x; 1.1172x over previous
//
#include <hip/hip_runtime.h>
#include <hip/hip_bf16.h>

#define NQ 4096
#define NK 8192
#define DQK 256
#define DA 64
#define NH 4
#define DOUT 256
#define NQT (NQ / 32)        // 128 q-tiles of 32
#define NSUP 8               // surviving partials per (h,qt): 8 key-regions
#define LOG2E 1.44269504088896340736f
#define QSCALE (0.125f * LOG2E)   // 1/sqrt(64) * log2(e), folded into Qp

typedef __attribute__((ext_vector_type(8))) short bf16x8;
typedef __attribute__((ext_vector_type(4))) float f32x4;
typedef __attribute__((ext_vector_type(2))) _Float16 f16x2;
typedef __attribute__((ext_vector_type(4))) _Float16 f16x4;
typedef __attribute__((ext_vector_type(8))) _Float16 f16x8;

__device__ inline unsigned short f2bf(float f) {
  union { float f; unsigned u; } v; v.f = f;
  unsigned r = v.u + 0x7fff + ((v.u >> 16) & 1);  // RNE
  return (unsigned short)(r >> 16);
}

__device__ inline f16x2 pkrtz(float a, float b) {
  return __builtin_bit_cast(f16x2, __builtin_amdgcn_cvt_pkrtz(a, b));
}

__device__ inline void gload16(const void* g, void* l) {
  __builtin_amdgcn_global_load_lds(
      (const __attribute__((address_space(1))) void*)g,
      (__attribute__((address_space(3))) void*)l, 16, 0, 0);
}

// ---------------------------------------------------------------------------
// 1. mask (int32 NQ x NK) -> TRANSPOSED bitmask bitsT[word32][row] (4 MB).
// ---------------------------------------------------------------------------
__global__ __launch_bounds__(256) void maskbits_kernel(
    const int* __restrict__ mask, unsigned* __restrict__ bitsT) {
  const int NW = 8192 * 4;                       // total waves
  int wid = blockIdx.x * 4 + (threadIdx.x >> 6);
  int lane = threadIdx.x & 63;
  for (int j = 0; j < 2; ++j) {
    int v[8];
#pragma unroll
    for (int u = 0; u < 8; ++u) {
      int c = wid + (j * 8 + u) * NW;   // u64 chunk id: row = c>>7, ch = c&127
      v[u] = mask[(size_t)(c >> 7) * NK + (c & 127) * 64 + lane];
    }
#pragma unroll
    for (int u = 0; u < 8; ++u) {
      unsigned long long b = __ballot(v[u] != 0);
      int c = wid + (j * 8 + u) * NW;
      int n = c >> 7, ch = c & 127;
      if (lane == 0)  bitsT[(size_t)(2 * ch) * NQ + n] = (unsigned)b;
      if (lane == 32) bitsT[(size_t)(2 * ch + 1) * NQ + n] = (unsigned)(b >> 32);
    }
  }
}

// ---------------------------------------------------------------------------
// 2. projections (unchanged from round 2).
// ---------------------------------------------------------------------------
__global__ __launch_bounds__(256) void proj_kernel(
    const float* __restrict__ xQ, const float* __restrict__ xK,
    const float* __restrict__ Wq, const float* __restrict__ Wk,
    const float* __restrict__ Wv,
    unsigned short* __restrict__ Qp, unsigned short* __restrict__ Kp,
    _Float16* __restrict__ Vf) {
  __shared__ __align__(16) unsigned short Wt[64][264];  // Wt[d][c], padded

  int b = blockIdx.x;
  int proj, h, rb;
  if (b < 128)       { proj = 0; h = b >> 5;  rb = b & 31; }
  else if (b < 384)  { proj = 1; b -= 128; h = b >> 6; rb = b & 63; }
  else               { proj = 2; b -= 384; h = b >> 6; rb = b & 63; }
  const float* x = (proj == 0) ? xQ : xK;
  const float* W = (proj == 0 ? Wq : (proj == 1 ? Wk : Wv)) + (size_t)h * 256 * 64;

  for (int i = threadIdx.x; i < 16384; i += 256)
    Wt[i & 63][i >> 6] = f2bf(W[i]);
  __syncthreads();

  int lane = threadIdx.x & 63, wv = threadIdx.x >> 6;
  int quad = lane >> 4, n16 = lane & 15;
  int r0 = rb * 128 + wv * 32;          // 32 rows per wave

  f32x4 acc[2][4];
#pragma unroll
  for (int mt = 0; mt < 2; ++mt)
#pragma unroll
    for (int nt = 0; nt < 4; ++nt)
      acc[mt][nt] = (f32x4){0.f, 0.f, 0.f, 0.f};

#pragma unroll
  for (int it = 0; it < 8; ++it) {
    const int k0 = it * 32;
    bf16x8 af[2];
#pragma unroll
    for (int mt = 0; mt < 2; ++mt) {
      const float* xp = x + (size_t)(r0 + mt * 16 + n16) * 256 + k0 + quad * 8;
      const float4 a0 = *(const float4*)xp;
      const float4 a1 = *(const float4*)(xp + 4);
      bf16x8 a;
      a[0] = (short)f2bf(a0.x); a[1] = (short)f2bf(a0.y);
      a[2] = (short)f2bf(a0.z); a[3] = (short)f2bf(a0.w);
      a[4] = (short)f2bf(a1.x); a[5] = (short)f2bf(a1.y);
      a[6] = (short)f2bf(a1.z); a[7] = (short)f2bf(a1.w);
      af[mt] = a;
    }
    bf16x8 bfr[4];
#pragma unroll
    for (int nt = 0; nt < 4; ++nt)
      bfr[nt] = *(const bf16x8*)&Wt[nt * 16 + n16][k0 + quad * 8];
#pragma unroll
    for (int mt = 0; mt < 2; ++mt)
#pragma unroll
      for (int nt = 0; nt < 4; ++nt)
        acc[mt][nt] = __builtin_amdgcn_mfma_f32_16x16x32_bf16(
            af[mt], bfr[nt], acc[mt][nt], 0, 0, 0);
  }

  if (proj < 2) {
    unsigned short* outp =
        (proj == 0 ? Qp : Kp) + (size_t)h * (size_t)(proj == 0 ? NQ : NK) * 64;
    const float sc = (proj == 0) ? QSCALE : 1.0f;
#pragma unroll
    for (int mt = 0; mt < 2; ++mt)
#pragma unroll
      for (int nt = 0; nt < 4; ++nt)
#pragma unroll
        for (int r = 0; r < 4; ++r) {
          int row = r0 + mt * 16 + quad * 4 + r;
          int col = nt * 16 + n16;
          outp[(size_t)row * 64 + col] = f2bf(acc[mt][nt][r] * sc);
        }
  } else {
    // K=32 fragment-linear V: tile = h*256 + keyblock32
    int tile = h * 256 + (r0 >> 5);
#pragma unroll
    for (int nt = 0; nt < 4; ++nt) {
      f16x8 pk;
      pk[0] = (_Float16)acc[0][nt][0]; pk[1] = (_Float16)acc[0][nt][1];
      pk[2] = (_Float16)acc[0][nt][2]; pk[3] = (_Float16)acc[0][nt][3];
      pk[4] = (_Float16)acc[1][nt][0]; pk[5] = (_Float16)acc[1][nt][1];
      pk[6] = (_Float16)acc[1][nt][2]; pk[7] = (_Float16)acc[1][nt][3];
      *(f16x8*)&Vf[(((size_t)tile * 4 + nt) * 64 + lane) * 8] = pk;
    }
  }
}

// ---------------------------------------------------------------------------
// 3. flash attention with async LDS staging (T3-min pipeline).
//    Block = (h, kp, 4 q-tiles): 4 waves share one 1024-key stream.
//    Per 64-key tile (16 KB: K 8KB frag-linear + V 8KB frag-linear):
//      - cooperative global_load_lds (4 x 1KB per wave), double-buffered;
//      - K's global source is per-lane PRE-SWIZZLED so the linear LDS dest
//        image is exactly QK-A-fragment order (global_load_lds can't scatter
//        its LDS side; the global side is per-lane free);
//      - compute reads via contiguous conflict-free ds_read_b128;
//      - one vmcnt(0)+s_barrier per tile: next tile's DMA is in flight for
//        the whole current-tile compute -> global latency decoupled.
//    v_cvt_pkrtz halves the P f32->f16 conversion ops.
// ---------------------------------------------------------------------------
__global__ __launch_bounds__(256, 4) void attn_kernel(
    const unsigned short* __restrict__ Qp, const unsigned short* __restrict__ Kp,
    const _Float16* __restrict__ Vf, const unsigned* __restrict__ bitsT,
    _Float16* __restrict__ Opart, float* __restrict__ Lpart) {
  __shared__ __align__(16) char lds[2][16384];   // [buf][K 8KB | V 8KB]

  // bijective XCD swizzle (8 XCDs, 1024 blocks, 128/chunk)
  int orig = blockIdx.x;
  int wgid = (orig & 7) * 128 + (orig >> 3);
  int qtg = wgid & 31;
  int combo = wgid >> 5;          // h*8 + kp: each XCD owns 4 combos, same h
  int kp = combo & 7, h = combo >> 3;

  int wv = threadIdx.x >> 6, lane = threadIdx.x & 63;
  int quad = lane >> 4, n16 = lane & 15;
  int qt = qtg * 4 + wv;          // this wave's q-tile
  int qb = qt * 32;

  // Q frags (bf16, pre-scaled by QSCALE)
  bf16x8 qf[2][2];
#pragma unroll
  for (int qc = 0; qc < 2; ++qc)
#pragma unroll
    for (int c = 0; c < 2; ++c)
      qf[qc][c] = *(const bf16x8*)&Qp[((size_t)h * NQ + qb + qc * 16 + n16) * 64 +
                                      c * 32 + quad * 8];

  f32x4 o[4][2];
#pragma unroll
  for (int dt = 0; dt < 4; ++dt)
#pragma unroll
    for (int qc = 0; qc < 2; ++qc) o[dt][qc] = (f32x4){0.f, 0.f, 0.f, 0.f};
  f32x4 o_l[2];
  o_l[0] = (f32x4){0.f, 0.f, 0.f, 0.f};
  o_l[1] = (f32x4){0.f, 0.f, 0.f, 0.f};

  f16x8 vones;
#pragma unroll
  for (int i = 0; i < 8; ++i) vones[i] = (_Float16)1.0f;

  const char* Kreg = (const char*)(Kp + (size_t)h * NK * 64 + (size_t)kp * 1024 * 64);
  const char* Vreg = (const char*)(Vf + ((size_t)h * 256 + kp * 32) * 2048);
  const unsigned* bT = bitsT + (size_t)(kp * 32) * NQ + qb;

  // per-lane source offsets for this wave's 4 staging instructions.
  // waves 0-1 stage K (swizzled source -> frag-linear LDS), waves 2-3 stage V
  // (already frag-linear in global -> linear copy).
  const char* sb;
  int soff[4];
  if (wv < 2) {
    sb = Kreg;
#pragma unroll
    for (int i = 0; i < 4; ++i) {
      int s = wv * 4096 + i * 1024 + lane * 16;
      int kb2 = s >> 12, rem = s & 4095, frag = rem >> 10;
      int kr = frag >> 1, c = frag & 1, ln = (rem >> 4) & 63;
      int q = ln >> 4, nn = ln & 15;
      soff[i] = ((kb2 * 32 + kr * 16 + nn) * 64 + c * 32 + q * 8) * 2;
    }
  } else {
    sb = Vreg;
#pragma unroll
    for (int i = 0; i < 4; ++i)
      soff[i] = (wv - 2) * 4096 + i * 1024 + lane * 16;
  }

  auto stage = [&](int t, int bufidx) {
    char* d = &lds[bufidx][wv * 4096];
    const char* s0 = sb + (size_t)t * 8192;
#pragma unroll
    for (int i = 0; i < 4; ++i)
      gload16(s0 + soff[i], d + i * 1024);
  };

  const int NT = 16;   // 1024 keys = 16 tiles of 64

  stage(0, 0);
  asm volatile("s_waitcnt vmcnt(0)" ::: "memory");
  __builtin_amdgcn_sched_barrier(0);
  __builtin_amdgcn_s_barrier();

  for (int t = 0; t < NT; ++t) {
    int cur = t & 1;
    if (t < NT - 1) stage(t + 1, cur ^ 1);

#pragma unroll
    for (int kb2 = 0; kb2 < 2; ++kb2) {
      int kb = t * 2 + kb2;
      unsigned wqa0 = bT[(size_t)kb * NQ + n16];
      unsigned wqa1 = bT[(size_t)kb * NQ + 16 + n16];

      const char* Kl = &lds[cur][kb2 * 4096];
      const char* Vl = &lds[cur][8192 + kb2 * 4096];

      bf16x8 kf[2][2];
#pragma unroll
      for (int kr = 0; kr < 2; ++kr)
#pragma unroll
        for (int c = 0; c < 2; ++c)
          kf[kr][c] = *(const bf16x8*)(Kl + (kr * 2 + c) * 1024 + lane * 16);

      f16x8 vf8[4];
#pragma unroll
      for (int dt = 0; dt < 4; ++dt)
        vf8[dt] = *(const f16x8*)(Vl + dt * 1024 + lane * 16);

      // S^T = K·Q^T (bf16 K=32, pre-scaled)
      f32x4 s[2][2];
#pragma unroll
      for (int kr = 0; kr < 2; ++kr)
#pragma unroll
        for (int qc = 0; qc < 2; ++qc) {
          f32x4 acc = (f32x4){0.f, 0.f, 0.f, 0.f};
          acc = __builtin_amdgcn_mfma_f32_16x16x32_bf16(kf[kr][0], qf[qc][0], acc, 0, 0, 0);
          acc = __builtin_amdgcn_mfma_f32_16x16x32_bf16(kf[kr][1], qf[qc][1], acc, 0, 0, 0);
          s[kr][qc] = acc;
        }

#pragma unroll
      for (int qc = 0; qc < 2; ++qc) {
        unsigned wq = (qc == 0 ? wqa0 : wqa1) >> (quad * 4);
        union { f16x8 v; f16x2 h[4]; } pu;
#pragma unroll
        for (int kr = 0; kr < 2; ++kr) {
          float e0 = __builtin_amdgcn_exp2f(s[kr][qc][0]);
          float e1 = __builtin_amdgcn_exp2f(s[kr][qc][1]);
          float e2 = __builtin_amdgcn_exp2f(s[kr][qc][2]);
          float e3 = __builtin_amdgcn_exp2f(s[kr][qc][3]);
          e0 = (wq & (1u << (kr * 16 + 0))) ? e0 : 0.f;
          e1 = (wq & (1u << (kr * 16 + 1))) ? e1 : 0.f;
          e2 = (wq & (1u << (kr * 16 + 2))) ? e2 : 0.f;
          e3 = (wq & (1u << (kr * 16 + 3))) ? e3 : 0.f;
          pu.h[kr * 2 + 0] = pkrtz(e0, e1);
          pu.h[kr * 2 + 1] = pkrtz(e2, e3);
        }
        // l-sum on the MFMA pipe: ones-A-frag, every reg = sum_k P[k][q]
        o_l[qc] = __builtin_amdgcn_mfma_f32_16x16x32_f16(vones, pu.v, o_l[qc], 0, 0, 0);
#pragma unroll
        for (int dt = 0; dt < 4; ++dt)
          o[dt][qc] = __builtin_amdgcn_mfma_f32_16x16x32_f16(vf8[dt], pu.v,
                                                             o[dt][qc], 0, 0, 0);
      }
    }

    asm volatile("s_waitcnt vmcnt(0)" ::: "memory");
    __builtin_amdgcn_sched_barrier(0);
    __builtin_amdgcn_s_barrier();
  }

  // ---- direct per-wave store (no cross-wave reduction needed)
  const size_t tile = ((size_t)h * NQT + qt) * NSUP + kp;
#pragma unroll
  for (int qc = 0; qc < 2; ++qc) {
#pragma unroll
    for (int dt = 0; dt < 4; ++dt) {
      union { f16x4 v; f16x2 h[2]; } u;
      u.h[0] = pkrtz(o[dt][qc][0], o[dt][qc][1]);
      u.h[1] = pkrtz(o[dt][qc][2], o[dt][qc][3]);
      *(f16x4*)&Opart[(tile * 32 + qc * 16 + n16) * 64 + dt * 16 + quad * 4] = u.v;
    }
    if (quad == 0) Lpart[tile * 32 + qc * 16 + n16] = o_l[qc][0];
  }
}

// ---------------------------------------------------------------------------
// 4. combine NSUP partials + fused gates + @Wo + bo. 256 blocks x 16 rows
// ---------------------------------------------------------------------------
__global__ __launch_bounds__(256) void combine_kernel(
    const _Float16* __restrict__ Opart, const float* __restrict__ Lpart,
    const float* __restrict__ xQ, const float* __restrict__ Wg,
    const float* __restrict__ bg, const float* __restrict__ Wo,
    const float* __restrict__ bo, float* __restrict__ out) {
  __shared__ float comb[16][64];
  __shared__ float gred[16][4][4];
  __shared__ float glds[16][4];
  int nb = blockIdx.x;
  int tid = threadIdx.x;

  // gates for this block's 16 rows
  {
    int r = tid >> 4, hh = (tid >> 2) & 3, c = tid & 3;
    const float* xp = xQ + (size_t)(nb * 16 + r) * 256 + c * 64;
    const float* wp = Wg + hh * 256 + c * 64;
    float s = 0.f;
#pragma unroll
    for (int e = 0; e < 64; ++e) s = fmaf(xp[e], wp[e], s);
    gred[r][hh][c] = s;
  }
  __syncthreads();
  if (tid < 64) {
    int r = tid >> 2, hh = tid & 3;
    float s = gred[r][hh][0] + gred[r][hh][1] + gred[r][hh][2] + gred[r][hh][3];
    glds[r][hh] = 1.f / (1.f + __expf(-(s + bg[hh])));
  }
  __syncthreads();

  int r4 = tid >> 6, a = tid & 63;
  int qt = nb >> 1, rbase = (nb & 1) * 16;

  for (int p = 0; p < 4; ++p) {
    int r = p * 4 + r4;
    int rl = rbase + r;
    float csum = 0.f;
#pragma unroll
    for (int h = 0; h < NH; ++h) {
      size_t t0 = ((size_t)h * NQT + qt) * NSUP;
      float accO = 0.f, lt = 0.f;
#pragma unroll
      for (int s = 0; s < NSUP; ++s) {
        size_t t = t0 + s;
        accO += (float)Opart[(t * 32 + rl) * 64 + a];
        lt += Lpart[t * 32 + rl];
      }
      csum += glds[r][h] * accO / lt;
    }
    comb[r][a] = csum;
  }
  __syncthreads();

  int j = tid;
  float accv[16];
#pragma unroll
  for (int r = 0; r < 16; ++r) accv[r] = bo[j];
  for (int aa = 0; aa < 64; ++aa) {
    float w = Wo[(size_t)aa * 256 + j];
#pragma unroll
    for (int r = 0; r < 16; ++r) accv[r] = fmaf(comb[r][aa], w, accv[r]);
  }
#pragma unroll
  for (int r = 0; r < 16; ++r)
    out[(size_t)(nb * 16 + r) * 256 + j] = accv[r];
}

// ---------------------------------------------------------------------------
extern "C" void kernel_launch(void* const* d_in, const int* in_sizes, int n_in,
                              void* d_out, int out_size, void* d_ws, size_t ws_size,
                              hipStream_t stream) {
  const float* xQ  = (const float*)d_in[0];
  const float* xK  = (const float*)d_in[1];
  const int*   mask= (const int*)d_in[2];
  const float* Wq  = (const float*)d_in[3];
  const float* Wk  = (const float*)d_in[4];
  const float* Wv  = (const float*)d_in[5];
  const float* Wg  = (const float*)d_in[6];
  const float* bg  = (const float*)d_in[7];
  const float* Wo  = (const float*)d_in[8];
  const float* bo  = (const float*)d_in[9];
  float* out = (float*)d_out;

  char* ws = (char*)d_ws;
  unsigned short* Qp   = (unsigned short*)(ws + 0);         // 2 MB   [H][NQ][64]
  unsigned short* Kp   = (unsigned short*)(ws + 2097152);   // 4 MB   [H][NK][64]
  _Float16*       Vfp  = (_Float16*)(ws + 6291456);         // 4 MB   frag-linear
  unsigned*       bitsT= (unsigned*)(ws + 10485760);        // 4 MB   [word][row]
  float*          Lp   = (float*)(ws + 14680064);           // 512 KB (4096 tiles)
  _Float16*       Op   = (_Float16*)(ws + 15204352);        // 16.8 MB f16

  maskbits_kernel<<<dim3(8192), dim3(256), 0, stream>>>(mask, bitsT);
  proj_kernel<<<dim3(640), dim3(256), 0, stream>>>(xQ, xK, Wq, Wk, Wv, Qp, Kp, Vfp);
  attn_kernel<<<dim3(1024), dim3(256), 0, stream>>>(Qp, Kp, Vfp, bitsT, Op, Lp);
  combine_kernel<<<dim3(NQ / 16), dim3(256), 0, stream>>>(Op, Lp, xQ, Wg, bg,
                                                          Wo, bo, out);
}

// Round 6
// 294.122 us; speedup vs baseline: 1.1544x; 1.0333x over previous
//
#include <hip/hip_runtime.h>
#include <hip/hip_bf16.h>

#define NQ 4096
#define NK 8192
#define DQK 256
#define DA 64
#define NH 4
#define DOUT 256
#define NQT (NQ / 32)        // 128 q-tiles of 32
#define NSUP 8               // surviving partials per (h,qt): 8 key-regions
#define LOG2E 1.44269504088896340736f
#define QSCALE (0.125f * LOG2E)   // 1/sqrt(64) * log2(e), folded into Qp

typedef __attribute__((ext_vector_type(8))) short bf16x8;
typedef __attribute__((ext_vector_type(4))) float f32x4;
typedef __attribute__((ext_vector_type(2))) _Float16 f16x2;
typedef __attribute__((ext_vector_type(4))) _Float16 f16x4;
typedef __attribute__((ext_vector_type(8))) _Float16 f16x8;

__device__ inline unsigned short f2bf(float f) {
  union { float f; unsigned u; } v; v.f = f;
  unsigned r = v.u + 0x7fff + ((v.u >> 16) & 1);  // RNE
  return (unsigned short)(r >> 16);
}

__device__ inline f16x2 pkrtz(float a, float b) {
  return __builtin_bit_cast(f16x2, __builtin_amdgcn_cvt_pkrtz(a, b));
}

__device__ inline void gload16(const void* g, void* l) {
  __builtin_amdgcn_global_load_lds(
      (const __attribute__((address_space(1))) void*)g,
      (__attribute__((address_space(3))) void*)l, 16, 0, 0);
}

// ---------------------------------------------------------------------------
// 1. mask (int32 NQ x NK) -> TRANSPOSED bitmask bitsT[word32][row] (4 MB).
// ---------------------------------------------------------------------------
__global__ __launch_bounds__(256) void maskbits_kernel(
    const int* __restrict__ mask, unsigned* __restrict__ bitsT) {
  const int NW = 8192 * 4;                       // total waves
  int wid = blockIdx.x * 4 + (threadIdx.x >> 6);
  int lane = threadIdx.x & 63;
  for (int j = 0; j < 2; ++j) {
    int v[8];
#pragma unroll
    for (int u = 0; u < 8; ++u) {
      int c = wid + (j * 8 + u) * NW;   // u64 chunk id: row = c>>7, ch = c&127
      v[u] = mask[(size_t)(c >> 7) * NK + (c & 127) * 64 + lane];
    }
#pragma unroll
    for (int u = 0; u < 8; ++u) {
      unsigned long long b = __ballot(v[u] != 0);
      int c = wid + (j * 8 + u) * NW;
      int n = c >> 7, ch = c & 127;
      if (lane == 0)  bitsT[(size_t)(2 * ch) * NQ + n] = (unsigned)b;
      if (lane == 32) bitsT[(size_t)(2 * ch + 1) * NQ + n] = (unsigned)(b >> 32);
    }
  }
}

// ---------------------------------------------------------------------------
// 2. projections (unchanged).
// ---------------------------------------------------------------------------
__global__ __launch_bounds__(256) void proj_kernel(
    const float* __restrict__ xQ, const float* __restrict__ xK,
    const float* __restrict__ Wq, const float* __restrict__ Wk,
    const float* __restrict__ Wv,
    unsigned short* __restrict__ Qp, unsigned short* __restrict__ Kp,
    _Float16* __restrict__ Vf) {
  __shared__ __align__(16) unsigned short Wt[64][264];  // Wt[d][c], padded

  int b = blockIdx.x;
  int proj, h, rb;
  if (b < 128)       { proj = 0; h = b >> 5;  rb = b & 31; }
  else if (b < 384)  { proj = 1; b -= 128; h = b >> 6; rb = b & 63; }
  else               { proj = 2; b -= 384; h = b >> 6; rb = b & 63; }
  const float* x = (proj == 0) ? xQ : xK;
  const float* W = (proj == 0 ? Wq : (proj == 1 ? Wk : Wv)) + (size_t)h * 256 * 64;

  for (int i = threadIdx.x; i < 16384; i += 256)
    Wt[i & 63][i >> 6] = f2bf(W[i]);
  __syncthreads();

  int lane = threadIdx.x & 63, wv = threadIdx.x >> 6;
  int quad = lane >> 4, n16 = lane & 15;
  int r0 = rb * 128 + wv * 32;          // 32 rows per wave

  f32x4 acc[2][4];
#pragma unroll
  for (int mt = 0; mt < 2; ++mt)
#pragma unroll
    for (int nt = 0; nt < 4; ++nt)
      acc[mt][nt] = (f32x4){0.f, 0.f, 0.f, 0.f};

#pragma unroll
  for (int it = 0; it < 8; ++it) {
    const int k0 = it * 32;
    bf16x8 af[2];
#pragma unroll
    for (int mt = 0; mt < 2; ++mt) {
      const float* xp = x + (size_t)(r0 + mt * 16 + n16) * 256 + k0 + quad * 8;
      const float4 a0 = *(const float4*)xp;
      const float4 a1 = *(const float4*)(xp + 4);
      bf16x8 a;
      a[0] = (short)f2bf(a0.x); a[1] = (short)f2bf(a0.y);
      a[2] = (short)f2bf(a0.z); a[3] = (short)f2bf(a0.w);
      a[4] = (short)f2bf(a1.x); a[5] = (short)f2bf(a1.y);
      a[6] = (short)f2bf(a1.z); a[7] = (short)f2bf(a1.w);
      af[mt] = a;
    }
    bf16x8 bfr[4];
#pragma unroll
    for (int nt = 0; nt < 4; ++nt)
      bfr[nt] = *(const bf16x8*)&Wt[nt * 16 + n16][k0 + quad * 8];
#pragma unroll
    for (int mt = 0; mt < 2; ++mt)
#pragma unroll
      for (int nt = 0; nt < 4; ++nt)
        acc[mt][nt] = __builtin_amdgcn_mfma_f32_16x16x32_bf16(
            af[mt], bfr[nt], acc[mt][nt], 0, 0, 0);
  }

  if (proj < 2) {
    unsigned short* outp =
        (proj == 0 ? Qp : Kp) + (size_t)h * (size_t)(proj == 0 ? NQ : NK) * 64;
    const float sc = (proj == 0) ? QSCALE : 1.0f;
#pragma unroll
    for (int mt = 0; mt < 2; ++mt)
#pragma unroll
      for (int nt = 0; nt < 4; ++nt)
#pragma unroll
        for (int r = 0; r < 4; ++r) {
          int row = r0 + mt * 16 + quad * 4 + r;
          int col = nt * 16 + n16;
          outp[(size_t)row * 64 + col] = f2bf(acc[mt][nt][r] * sc);
        }
  } else {
    // K=32 fragment-linear V: tile = h*256 + keyblock32
    int tile = h * 256 + (r0 >> 5);
#pragma unroll
    for (int nt = 0; nt < 4; ++nt) {
      f16x8 pk;
      pk[0] = (_Float16)acc[0][nt][0]; pk[1] = (_Float16)acc[0][nt][1];
      pk[2] = (_Float16)acc[0][nt][2]; pk[3] = (_Float16)acc[0][nt][3];
      pk[4] = (_Float16)acc[1][nt][0]; pk[5] = (_Float16)acc[1][nt][1];
      pk[6] = (_Float16)acc[1][nt][2]; pk[7] = (_Float16)acc[1][nt][3];
      *(f16x8*)&Vf[(((size_t)tile * 4 + nt) * 64 + lane) * 8] = pk;
    }
  }
}

// ---------------------------------------------------------------------------
// 3. flash attention, depth-2 async pipeline (counted vmcnt, never drain-0).
//    Block = (h, kp, 4 q-tiles). Tile = 32 keys (8 KB: K 4KB + V 4KB,
//    both fragment-linear in LDS), 3 LDS buffers (24 KB).
//    Per tile t: issue stage(t+2) -> load bits(t+1) -> compute(t) ->
//    s_waitcnt vmcnt(4) (waits ONLY stage(t+1), leaves stage(t+2)+bits
//    in flight) -> s_barrier. DMA gets ~2 tile-times of slack instead of ~1.
// ---------------------------------------------------------------------------
__global__ __launch_bounds__(256, 4) void attn_kernel(
    const unsigned short* __restrict__ Qp, const unsigned short* __restrict__ Kp,
    const _Float16* __restrict__ Vf, const unsigned* __restrict__ bitsT,
    _Float16* __restrict__ Opart, float* __restrict__ Lpart) {
  __shared__ __align__(16) char lds[3][8192];   // [buf][K 4KB | V 4KB]

  // bijective XCD swizzle (8 XCDs, 1024 blocks, 128/chunk)
  int orig = blockIdx.x;
  int wgid = (orig & 7) * 128 + (orig >> 3);
  int qtg = wgid & 31;
  int combo = wgid >> 5;          // h*8 + kp: each XCD owns 4 combos, same h
  int kp = combo & 7, h = combo >> 3;

  int wv = threadIdx.x >> 6, lane = threadIdx.x & 63;
  int quad = lane >> 4, n16 = lane & 15;
  int qt = qtg * 4 + wv;          // this wave's q-tile
  int qb = qt * 32;

  // Q frags (bf16, pre-scaled by QSCALE)
  bf16x8 qf[2][2];
#pragma unroll
  for (int qc = 0; qc < 2; ++qc)
#pragma unroll
    for (int c = 0; c < 2; ++c)
      qf[qc][c] = *(const bf16x8*)&Qp[((size_t)h * NQ + qb + qc * 16 + n16) * 64 +
                                      c * 32 + quad * 8];

  f32x4 o[4][2];
#pragma unroll
  for (int dt = 0; dt < 4; ++dt)
#pragma unroll
    for (int qc = 0; qc < 2; ++qc) o[dt][qc] = (f32x4){0.f, 0.f, 0.f, 0.f};
  f32x4 o_l[2];
  o_l[0] = (f32x4){0.f, 0.f, 0.f, 0.f};
  o_l[1] = (f32x4){0.f, 0.f, 0.f, 0.f};

  f16x8 vones;
#pragma unroll
  for (int i = 0; i < 8; ++i) vones[i] = (_Float16)1.0f;

  const char* Kreg = (const char*)(Kp + (size_t)h * NK * 64 + (size_t)kp * 1024 * 64);
  const char* Vreg = (const char*)(Vf + ((size_t)h * 256 + kp * 32) * 2048);
  const unsigned* bT = bitsT + (size_t)(kp * 32) * NQ + qb;

  // per-lane source offsets: each wave stages 2 KB of the 8 KB tile image.
  // waves 0-1: K (pre-swizzled source -> frag-linear LDS), kr = wv, c = i.
  // waves 2-3: V (already frag-linear in global -> linear copy).
  const char* sb;
  int soff[2];
  if (wv < 2) {
    sb = Kreg;
#pragma unroll
    for (int i = 0; i < 2; ++i)
      soff[i] = ((wv * 16 + n16) * 64 + i * 32 + quad * 8) * 2;
  } else {
    sb = Vreg;
#pragma unroll
    for (int i = 0; i < 2; ++i)
      soff[i] = (wv - 2) * 2048 + i * 1024 + lane * 16;
  }

  auto stage = [&](int t, int bufidx) {
    char* d = &lds[bufidx][wv * 2048];
    const char* s0 = sb + (size_t)t * 4096;
#pragma unroll
    for (int i = 0; i < 2; ++i)
      gload16(s0 + soff[i], d + i * 1024);
  };

  auto compute = [&](int buf, unsigned wqa0, unsigned wqa1) {
    const char* Kl = lds[buf];
    const char* Vl = lds[buf] + 4096;

    bf16x8 kf[2][2];
#pragma unroll
    for (int kr = 0; kr < 2; ++kr)
#pragma unroll
      for (int c = 0; c < 2; ++c)
        kf[kr][c] = *(const bf16x8*)(Kl + (kr * 2 + c) * 1024 + lane * 16);

    // S^T = K·Q^T (bf16 K=32, pre-scaled)
    f32x4 s[2][2];
#pragma unroll
    for (int kr = 0; kr < 2; ++kr)
#pragma unroll
      for (int qc = 0; qc < 2; ++qc) {
        f32x4 acc = (f32x4){0.f, 0.f, 0.f, 0.f};
        acc = __builtin_amdgcn_mfma_f32_16x16x32_bf16(kf[kr][0], qf[qc][0], acc, 0, 0, 0);
        acc = __builtin_amdgcn_mfma_f32_16x16x32_bf16(kf[kr][1], qf[qc][1], acc, 0, 0, 0);
        s[kr][qc] = acc;
      }

    f16x8 vf8[4];
#pragma unroll
    for (int dt = 0; dt < 4; ++dt)
      vf8[dt] = *(const f16x8*)(Vl + dt * 1024 + lane * 16);

#pragma unroll
    for (int qc = 0; qc < 2; ++qc) {
      unsigned wq = (qc == 0 ? wqa0 : wqa1) >> (quad * 4);
      union { f16x8 v; f16x2 h[4]; } pu;
#pragma unroll
      for (int kr = 0; kr < 2; ++kr) {
        float e0 = __builtin_amdgcn_exp2f(s[kr][qc][0]);
        float e1 = __builtin_amdgcn_exp2f(s[kr][qc][1]);
        float e2 = __builtin_amdgcn_exp2f(s[kr][qc][2]);
        float e3 = __builtin_amdgcn_exp2f(s[kr][qc][3]);
        e0 = (wq & (1u << (kr * 16 + 0))) ? e0 : 0.f;
        e1 = (wq & (1u << (kr * 16 + 1))) ? e1 : 0.f;
        e2 = (wq & (1u << (kr * 16 + 2))) ? e2 : 0.f;
        e3 = (wq & (1u << (kr * 16 + 3))) ? e3 : 0.f;
        pu.h[kr * 2 + 0] = pkrtz(e0, e1);
        pu.h[kr * 2 + 1] = pkrtz(e2, e3);
      }
      // l-sum on the MFMA pipe: ones-A-frag, every reg = sum_k P[k][q]
      o_l[qc] = __builtin_amdgcn_mfma_f32_16x16x32_f16(vones, pu.v, o_l[qc], 0, 0, 0);
#pragma unroll
      for (int dt = 0; dt < 4; ++dt)
        o[dt][qc] = __builtin_amdgcn_mfma_f32_16x16x32_f16(vf8[dt], pu.v,
                                                           o[dt][qc], 0, 0, 0);
    }
  };

  // ---- prologue: bits(0), stage(0), stage(1); wait stage(0) only
  unsigned cw0 = bT[n16], cw1 = bT[16 + n16];
  stage(0, 0);
  stage(1, 1);
  asm volatile("s_waitcnt vmcnt(2)" ::: "memory");
  __builtin_amdgcn_sched_barrier(0);
  __builtin_amdgcn_s_barrier();

  // ---- main loop: 30 full-pipeline tiles (unroll 3 -> constant buf indices)
#pragma unroll 3
  for (int t = 0; t < 30; ++t) {
    stage(t + 2, (t + 2) % 3);
    unsigned nw0 = bT[(size_t)(t + 1) * NQ + n16];
    unsigned nw1 = bT[(size_t)(t + 1) * NQ + 16 + n16];
    compute(t % 3, cw0, cw1);
    cw0 = nw0; cw1 = nw1;
    asm volatile("s_waitcnt vmcnt(4)" ::: "memory");
    __builtin_amdgcn_sched_barrier(0);
    __builtin_amdgcn_s_barrier();
  }
  // t = 30: no stage; wait stage(31)
  {
    unsigned nw0 = bT[(size_t)31 * NQ + n16];
    unsigned nw1 = bT[(size_t)31 * NQ + 16 + n16];
    compute(0, cw0, cw1);
    cw0 = nw0; cw1 = nw1;
    asm volatile("s_waitcnt vmcnt(2)" ::: "memory");
    __builtin_amdgcn_sched_barrier(0);
    __builtin_amdgcn_s_barrier();
  }
  // t = 31: compute only
  compute(1, cw0, cw1);

  // ---- direct per-wave store (no cross-wave reduction needed)
  const size_t tile = ((size_t)h * NQT + qt) * NSUP + kp;
#pragma unroll
  for (int qc = 0; qc < 2; ++qc) {
#pragma unroll
    for (int dt = 0; dt < 4; ++dt) {
      union { f16x4 v; f16x2 h[2]; } u;
      u.h[0] = pkrtz(o[dt][qc][0], o[dt][qc][1]);
      u.h[1] = pkrtz(o[dt][qc][2], o[dt][qc][3]);
      *(f16x4*)&Opart[(tile * 32 + qc * 16 + n16) * 64 + dt * 16 + quad * 4] = u.v;
    }
    if (quad == 0) Lpart[tile * 32 + qc * 16 + n16] = o_l[qc][0];
  }
}

// ---------------------------------------------------------------------------
// 4. combine NSUP partials + fused gates + @Wo + bo.
//    512 blocks x 8 rows; Opart read as f16x2 (paired a) -> half the loads.
// ---------------------------------------------------------------------------
__global__ __launch_bounds__(256) void combine_kernel(
    const _Float16* __restrict__ Opart, const float* __restrict__ Lpart,
    const float* __restrict__ xQ, const float* __restrict__ Wg,
    const float* __restrict__ bg, const float* __restrict__ Wo,
    const float* __restrict__ bo, float* __restrict__ out) {
  __shared__ float comb[8][64];
  __shared__ float gred[32][8];
  __shared__ float glds[8][4];
  int nb = blockIdx.x;
  int tid = threadIdx.x;
  int row0 = nb * 8;

  // gates for this block's 8 rows x 4 heads (32 dots, 8-way split each)
  {
    int rh = tid >> 3, c = tid & 7;
    int r = rh >> 2, hh = rh & 3;
    const float* xp = xQ + (size_t)(row0 + r) * 256 + c * 32;
    const float* wp = Wg + hh * 256 + c * 32;
    float s = 0.f;
#pragma unroll
    for (int e = 0; e < 32; ++e) s = fmaf(xp[e], wp[e], s);
    gred[rh][c] = s;
  }
  __syncthreads();
  if (tid < 32) {
    float s = 0.f;
#pragma unroll
    for (int c = 0; c < 8; ++c) s += gred[tid][c];
    glds[tid >> 2][tid & 3] = 1.f / (1.f + __expf(-(s + bg[tid & 3])));
  }
  __syncthreads();

  int qt = nb >> 2, rbase = (nb & 3) * 8;
  {
    int athr = tid & 31, r = tid >> 5;      // 32 a-pairs x 8 rows
    int rl = rbase + r;
    int a0 = athr * 2;
    float c0 = 0.f, c1 = 0.f;
#pragma unroll
    for (int hh = 0; hh < NH; ++hh) {
      size_t t0 = ((size_t)hh * NQT + qt) * NSUP;
      float a0s = 0.f, a1s = 0.f, lt = 0.f;
#pragma unroll
      for (int s = 0; s < NSUP; ++s) {
        size_t t = t0 + s;
        f16x2 v = *(const f16x2*)&Opart[(t * 32 + rl) * 64 + a0];
        a0s += (float)v[0];
        a1s += (float)v[1];
        lt += Lpart[t * 32 + rl];
      }
      float g = glds[r][hh] / lt;
      c0 = fmaf(g, a0s, c0);
      c1 = fmaf(g, a1s, c1);
    }
    comb[r][a0] = c0;
    comb[r][a0 + 1] = c1;
  }
  __syncthreads();

  int j = tid;
  float accv[8];
#pragma unroll
  for (int r = 0; r < 8; ++r) accv[r] = bo[j];
  for (int aa = 0; aa < 64; ++aa) {
    float w = Wo[(size_t)aa * 256 + j];
#pragma unroll
    for (int r = 0; r < 8; ++r) accv[r] = fmaf(comb[r][aa], w, accv[r]);
  }
#pragma unroll
  for (int r = 0; r < 8; ++r)
    out[(size_t)(row0 + r) * 256 + j] = accv[r];
}

// ---------------------------------------------------------------------------
extern "C" void kernel_launch(void* const* d_in, const int* in_sizes, int n_in,
                              void* d_out, int out_size, void* d_ws, size_t ws_size,
                              hipStream_t stream) {
  const float* xQ  = (const float*)d_in[0];
  const float* xK  = (const float*)d_in[1];
  const int*   mask= (const int*)d_in[2];
  const float* Wq  = (const float*)d_in[3];
  const float* Wk  = (const float*)d_in[4];
  const float* Wv  = (const float*)d_in[5];
  const float* Wg  = (const float*)d_in[6];
  const float* bg  = (const float*)d_in[7];
  const float* Wo  = (const float*)d_in[8];
  const float* bo  = (const float*)d_in[9];
  float* out = (float*)d_out;

  char* ws = (char*)d_ws;
  unsigned short* Qp   = (unsigned short*)(ws + 0);         // 2 MB   [H][NQ][64]
  unsigned short* Kp   = (unsigned short*)(ws + 2097152);   // 4 MB   [H][NK][64]
  _Float16*       Vfp  = (_Float16*)(ws + 6291456);         // 4 MB   frag-linear
  unsigned*       bitsT= (unsigned*)(ws + 10485760);        // 4 MB   [word][row]
  float*          Lp   = (float*)(ws + 14680064);           // 512 KB (4096 tiles)
  _Float16*       Op   = (_Float16*)(ws + 15204352);        // 16.8 MB f16

  maskbits_kernel<<<dim3(8192), dim3(256), 0, stream>>>(mask, bitsT);
  proj_kernel<<<dim3(640), dim3(256), 0, stream>>>(xQ, xK, Wq, Wk, Wv, Qp, Kp, Vfp);
  attn_kernel<<<dim3(1024), dim3(256), 0, stream>>>(Qp, Kp, Vfp, bitsT, Op, Lp);
  combine_kernel<<<dim3(NQ / 8), dim3(256), 0, stream>>>(Op, Lp, xQ, Wg, bg,
                                                         Wo, bo, out);
}